// Round 2
// baseline (1898.327 us; speedup 1.0000x reference)
//
#include <hip/hip_runtime.h>
#include <hip/hip_bf16.h>
#include <math.h>

typedef __bf16 bf16x8 __attribute__((ext_vector_type(8)));
typedef __bf16 bf16x4 __attribute__((ext_vector_type(4)));
typedef float f32x4 __attribute__((ext_vector_type(4)));

typedef __attribute__((address_space(1))) void GV;
typedef __attribute__((address_space(3))) void LV;

// ---------------------------------------------------------------------------
// cvt_x: fp32 -> bf16, vectorized (float4 in, 4x bf16 out)
// ---------------------------------------------------------------------------
__global__ __launch_bounds__(256) void cvt_x_kernel(const float4* __restrict__ in,
                                                    __bf16* __restrict__ out) {
  size_t i = (size_t)blockIdx.x * 256 + threadIdx.x;
  float4 v = in[i];
  bf16x4 o;
  o.x = (__bf16)v.x; o.y = (__bf16)v.y; o.z = (__bf16)v.z; o.w = (__bf16)v.w;
  ((bf16x4*)out)[i] = o;
}

// ---------------------------------------------------------------------------
// transpose_cvt<OSTRIDE, EBLOCK>: per-expert [R=2048][C=2048] fp32 transpose
// -> bf16.
//   EBLOCK=true : out[e][c][r]            (flat e*4M + c*OSTRIDE + r), OSTRIDE=2048
//   EBLOCK=false: out[c*OSTRIDE + e*2048 + r]  — for GEMM2's [o][e*2048+h] view,
//                 OSTRIDE=8192 (w2t[o][e][h] = w2[e][h][o])
// ---------------------------------------------------------------------------
template <int OSTRIDE, bool EBLOCK>
__global__ __launch_bounds__(256) void transpose_cvt(const float* __restrict__ in,
                                                     __bf16* __restrict__ out) {
  __shared__ float tile[32][33];
  const int e = blockIdx.z;
  const size_t ibase = (size_t)e * 2048 * 2048;
  const size_t obase = EBLOCK ? (size_t)e * 2048 * 2048 : (size_t)e * 2048;
  int c0 = blockIdx.x * 32, r0 = blockIdx.y * 32;
  int tx = threadIdx.x & 31, ty = threadIdx.x >> 5;  // ty in 0..7
#pragma unroll
  for (int i = 0; i < 32; i += 8)
    tile[ty + i][tx] = in[ibase + (size_t)(r0 + ty + i) * 2048 + c0 + tx];
  __syncthreads();
#pragma unroll
  for (int i = 0; i < 32; i += 8)
    out[obase + (size_t)(c0 + ty + i) * OSTRIDE + r0 + tx] = (__bf16)tile[tx][ty + i];
}

// ---------------------------------------------------------------------------
// router: logits -> softmax(fp32) -> top-2 -> renorm -> dense combine [N][4]
// one wave per token, fp32 throughout (expert SELECTION must be exact-ish)
// ---------------------------------------------------------------------------
__global__ __launch_bounds__(256) void router_kernel(const float* __restrict__ x,
                                                     const float* __restrict__ gw,
                                                     float* __restrict__ comb) {
  int lane = threadIdx.x & 63;
  int wv = threadIdx.x >> 6;
  int n = blockIdx.x * 4 + wv;
  const float* xr = x + (size_t)n * 2048;
  float s0 = 0.f, s1 = 0.f, s2 = 0.f, s3 = 0.f;
  for (int d = lane; d < 2048; d += 64) {
    float xv = xr[d];
    s0 += xv * gw[d];
    s1 += xv * gw[2048 + d];
    s2 += xv * gw[4096 + d];
    s3 += xv * gw[6144 + d];
  }
#pragma unroll
  for (int off = 32; off > 0; off >>= 1) {
    s0 += __shfl_down(s0, off);
    s1 += __shfl_down(s1, off);
    s2 += __shfl_down(s2, off);
    s3 += __shfl_down(s3, off);
  }
  if (lane == 0) {
    float l[4] = {s0, s1, s2, s3};
    float m = fmaxf(fmaxf(l[0], l[1]), fmaxf(l[2], l[3]));
    float p[4], sum = 0.f;
#pragma unroll
    for (int e = 0; e < 4; ++e) { p[e] = expf(l[e] - m); sum += p[e]; }
#pragma unroll
    for (int e = 0; e < 4; ++e) p[e] /= sum;
    int i1 = 0;
#pragma unroll
    for (int e = 1; e < 4; ++e) if (p[e] > p[i1]) i1 = e;
    int i2 = -1;
#pragma unroll
    for (int e = 0; e < 4; ++e) {
      if (e == i1) continue;
      if (i2 < 0 || p[e] > p[i2]) i2 = e;
    }
    float ws = p[i1] + p[i2];
#pragma unroll
    for (int e = 0; e < 4; ++e)
      comb[(size_t)n * 4 + e] = (e == i1 || e == i2) ? p[e] / ws : 0.f;
  }
}

// ---------------------------------------------------------------------------
// gemm_bt<MODE>: C = A[M,K] @ Bt[Nout,K]^T, 128x128 tile, BK=32,
// mfma_f32_16x16x32_bf16, global_load_lds width-16 staging (m97 structure).
// MODE 0: GEMM1  K=2048, Nout=8192: epilogue +b1, exact gelu, *combine -> bf16 h1s
// MODE 1: GEMM2  K=8192, Nout=2048: epilogue + sum_e comb*b2 -> fp32 out
// M per launch = 4096 (one token chunk); all dims divide evenly, no bounds checks.
// ---------------------------------------------------------------------------
template <int MODE>
__global__ __launch_bounds__(256) void gemm_bt(const __bf16* __restrict__ A,
                                               const __bf16* __restrict__ Bt,
                                               const float* __restrict__ bias,
                                               const float* __restrict__ comb,
                                               void* __restrict__ outp) {
  constexpr int K = (MODE == 0) ? 2048 : 8192;
  __shared__ __bf16 ldsA[128 * 32];
  __shared__ __bf16 ldsB[128 * 32];

  const int tid = threadIdx.x;
  const int lane = tid & 63;
  const int wv = tid >> 6;
  const int bx = blockIdx.x, by = blockIdx.y;

  const int lrow = lane & 15;   // A-row / B-col within 16x16 tile
  const int quad = lane >> 4;   // k-group: k = quad*8 + j
  const int mbase = (wv >> 1) * 64;
  const int nbase = (wv & 1) * 64;

  f32x4 acc[4][4] = {};

  for (int kb = 0; kb < K / 32; ++kb) {
    __syncthreads();  // protect LDS from previous iteration's readers
#pragma unroll
    for (int t = 0; t < 2; ++t) {
      int g = t * 256 + wv * 64 + lane;  // 16B-chunk id, 0..511
      int row = g >> 2, kc = g & 3;
      const __bf16* ga = A + (size_t)(by * 128 + row) * K + kb * 32 + kc * 8;
      const __bf16* gb = Bt + (size_t)(bx * 128 + row) * K + kb * 32 + kc * 8;
      int loff = t * 2048 + wv * 512;  // wave-uniform LDS base (elements); HW adds lane*16B
      __builtin_amdgcn_global_load_lds((GV*)ga, (LV*)&ldsA[loff], 16, 0, 0);
      __builtin_amdgcn_global_load_lds((GV*)gb, (LV*)&ldsB[loff], 16, 0, 0);
    }
    __syncthreads();  // compiler emits vmcnt(0) drain before s_barrier

    bf16x8 af[4], bfr[4];
#pragma unroll
    for (int i = 0; i < 4; ++i)
      af[i] = *(const bf16x8*)&ldsA[(mbase + i * 16 + lrow) * 32 + quad * 8];
#pragma unroll
    for (int i = 0; i < 4; ++i)
      bfr[i] = *(const bf16x8*)&ldsB[(nbase + i * 16 + lrow) * 32 + quad * 8];
#pragma unroll
    for (int mi = 0; mi < 4; ++mi)
#pragma unroll
      for (int ni = 0; ni < 4; ++ni)
        acc[mi][ni] = __builtin_amdgcn_mfma_f32_16x16x32_bf16(af[mi], bfr[ni],
                                                              acc[mi][ni], 0, 0, 0);
  }

  // epilogue: C/D layout col = lane&15, row = quad*4 + reg  [m89/m91 verified]
#pragma unroll
  for (int mi = 0; mi < 4; ++mi) {
#pragma unroll
    for (int ni = 0; ni < 4; ++ni) {
      int gcol = bx * 128 + nbase + ni * 16 + lrow;
      int grow0 = by * 128 + mbase + mi * 16 + quad * 4;
      f32x4 v = acc[mi][ni];
      if (MODE == 0) {
        int e = gcol >> 11;
        int h = gcol & 2047;
        float b = bias[e * 2048 + h];
        __bf16* out = (__bf16*)outp;
#pragma unroll
        for (int r = 0; r < 4; ++r) {
          int row = grow0 + r;
          float xv = v[r] + b;
          float gl = 0.5f * xv * (1.0f + erff(xv * 0.70710678118654752440f));
          out[(size_t)row * 8192 + gcol] = (__bf16)(gl * comb[row * 4 + e]);
        }
      } else {
        float* out = (float*)outp;
        float bb0 = bias[gcol], bb1 = bias[2048 + gcol];
        float bb2 = bias[4096 + gcol], bb3 = bias[6144 + gcol];
#pragma unroll
        for (int r = 0; r < 4; ++r) {
          int row = grow0 + r;
          const float* cw = comb + (size_t)row * 4;
          float s = v[r] + cw[0] * bb0 + cw[1] * bb1 + cw[2] * bb2 + cw[3] * bb3;
          out[(size_t)row * 2048 + gcol] = s;
        }
      }
    }
  }
}

// ---------------------------------------------------------------------------
// launch
// ---------------------------------------------------------------------------
extern "C" void kernel_launch(void* const* d_in, const int* in_sizes, int n_in,
                              void* d_out, int out_size, void* d_ws, size_t ws_size,
                              hipStream_t stream) {
  const float* hs = (const float*)d_in[0];      // [8,2048,2048]
  const float* gate_w = (const float*)d_in[1];  // [4,2048]
  const float* w1 = (const float*)d_in[2];      // [4,2048,2048]
  const float* b1 = (const float*)d_in[3];      // [4,2048]
  const float* w2 = (const float*)d_in[4];      // [4,2048,2048]
  const float* b2 = (const float*)d_in[5];      // [4,2048]
  float* out = (float*)d_out;

  const int N = 16384;  // tokens
  const int D = 2048, H = 2048, E = 4;
  const int CHUNK = 4096;  // token chunk so h1s fits in ws

  char* p = (char*)d_ws;
  __bf16* xb = (__bf16*)p;  p += (size_t)N * D * 2;       //  64 MiB
  __bf16* w1t = (__bf16*)p; p += (size_t)E * D * H * 2;   //  32 MiB  [e][h][d]
  __bf16* w2t = (__bf16*)p; p += (size_t)E * H * H * 2;   //  32 MiB  [o][e*2048+h]
  float* comb = (float*)p;  p += (size_t)N * 4 * 4;       // 256 KiB
  __bf16* h1s = (__bf16*)p;                               //  64 MiB  [CHUNK][E*H]

  cvt_x_kernel<<<dim3((N * D / 4) / 256), 256, 0, stream>>>((const float4*)hs, xb);
  transpose_cvt<2048, true><<<dim3(64, 64, 4), 256, 0, stream>>>(w1, w1t);
  transpose_cvt<8192, false><<<dim3(64, 64, 4), 256, 0, stream>>>(w2, w2t);
  router_kernel<<<dim3(N / 4), 256, 0, stream>>>(hs, gate_w, comb);

  for (int c = 0; c < N / CHUNK; ++c) {
    const __bf16* Ax = xb + (size_t)c * CHUNK * D;
    const float* cc = comb + (size_t)c * CHUNK * 4;
    gemm_bt<0><<<dim3(E * H / 128, CHUNK / 128), 256, 0, stream>>>(Ax, w1t, b1, cc, h1s);
    gemm_bt<1><<<dim3(H / 128, CHUNK / 128), 256, 0, stream>>>(h1s, w2t, b2, cc,
                                                               out + (size_t)c * CHUNK * H);
  }
}

// Round 3
// 1694.332 us; speedup vs baseline: 1.1204x; 1.1204x over previous
//
#include <hip/hip_runtime.h>
#include <hip/hip_bf16.h>
#include <math.h>

typedef __bf16 bf16x8 __attribute__((ext_vector_type(8)));
typedef __bf16 bf16x4 __attribute__((ext_vector_type(4)));
typedef float f32x4 __attribute__((ext_vector_type(4)));

typedef __attribute__((address_space(1))) void GV;
typedef __attribute__((address_space(3))) void LV;

// ---------------------------------------------------------------------------
// transpose_cvt<OSTRIDE, EBLOCK>: per-expert [R=2048][C=2048] fp32 -> bf16 ^T
//   EBLOCK=true : out[e][c][r]                 OSTRIDE=2048   (w1t for GEMM1)
//   EBLOCK=false: out[c*OSTRIDE + e*2048 + r]  OSTRIDE=8192   (w2t for GEMM2)
// ---------------------------------------------------------------------------
template <int OSTRIDE, bool EBLOCK>
__global__ __launch_bounds__(256) void transpose_cvt(const float* __restrict__ in,
                                                     __bf16* __restrict__ out) {
  __shared__ float tile[32][33];
  const int e = blockIdx.z;
  const size_t ibase = (size_t)e * 2048 * 2048;
  const size_t obase = EBLOCK ? (size_t)e * 2048 * 2048 : (size_t)e * 2048;
  int c0 = blockIdx.x * 32, r0 = blockIdx.y * 32;
  int tx = threadIdx.x & 31, ty = threadIdx.x >> 5;
#pragma unroll
  for (int i = 0; i < 32; i += 8)
    tile[ty + i][tx] = in[ibase + (size_t)(r0 + ty + i) * 2048 + c0 + tx];
  __syncthreads();
#pragma unroll
  for (int i = 0; i < 32; i += 8)
    out[obase + (size_t)(c0 + ty + i) * OSTRIDE + r0 + tx] = (__bf16)tile[tx][ty + i];
}

// ---------------------------------------------------------------------------
// router: logits -> softmax(fp32) -> top-2 -> renorm -> dense combine [N][4]
// plus pair-id (0..5 over C(4,2)) and bucket histogram.
// ---------------------------------------------------------------------------
__global__ __launch_bounds__(256) void router_kernel(const float* __restrict__ x,
                                                     const float* __restrict__ gw,
                                                     float* __restrict__ comb,
                                                     int* __restrict__ pairid,
                                                     int* __restrict__ cnt) {
  int lane = threadIdx.x & 63;
  int wv = threadIdx.x >> 6;
  int n = blockIdx.x * 4 + wv;
  const float* xr = x + (size_t)n * 2048;
  float s0 = 0.f, s1 = 0.f, s2 = 0.f, s3 = 0.f;
  for (int d = lane; d < 2048; d += 64) {
    float xv = xr[d];
    s0 += xv * gw[d];
    s1 += xv * gw[2048 + d];
    s2 += xv * gw[4096 + d];
    s3 += xv * gw[6144 + d];
  }
#pragma unroll
  for (int off = 32; off > 0; off >>= 1) {
    s0 += __shfl_down(s0, off);
    s1 += __shfl_down(s1, off);
    s2 += __shfl_down(s2, off);
    s3 += __shfl_down(s3, off);
  }
  if (lane == 0) {
    float l[4] = {s0, s1, s2, s3};
    float m = fmaxf(fmaxf(l[0], l[1]), fmaxf(l[2], l[3]));
    float p[4], sum = 0.f;
#pragma unroll
    for (int e = 0; e < 4; ++e) { p[e] = expf(l[e] - m); sum += p[e]; }
#pragma unroll
    for (int e = 0; e < 4; ++e) p[e] /= sum;
    int i1 = 0;
#pragma unroll
    for (int e = 1; e < 4; ++e) if (p[e] > p[i1]) i1 = e;
    int i2 = -1;
#pragma unroll
    for (int e = 0; e < 4; ++e) {
      if (e == i1) continue;
      if (i2 < 0 || p[e] > p[i2]) i2 = e;
    }
    float ws = p[i1] + p[i2];
#pragma unroll
    for (int e = 0; e < 4; ++e)
      comb[(size_t)n * 4 + e] = (e == i1 || e == i2) ? p[e] / ws : 0.f;
    int a = min(i1, i2), b = max(i1, i2);
    int pid = (a == 0) ? (b - 1) : ((a == 1) ? (1 + b) : (2 + b));
    pairid[n] = pid;
    atomicAdd(&cnt[pid], 1);
  }
}

// exclusive scan over 6 bucket counts (1 thread)
__global__ void scan6(const int* __restrict__ cnt, int* __restrict__ off) {
  int o = 0;
  for (int i = 0; i < 6; ++i) { off[i] = o; o += cnt[i]; }
}

// assign sorted positions; gather combine weights + pair bitmask into sorted order
__global__ __launch_bounds__(256) void assign_kernel(const int* __restrict__ pairid,
                                                     const float4* __restrict__ comb4,
                                                     const int* __restrict__ off,
                                                     int* __restrict__ cur,
                                                     int* __restrict__ perm,
                                                     float4* __restrict__ comb_s,
                                                     int* __restrict__ pm_s) {
  int n = blockIdx.x * 256 + threadIdx.x;
  int pid = pairid[n];
  int pos = off[pid] + atomicAdd(&cur[pid], 1);
  perm[pos] = n;
  comb_s[pos] = comb4[n];
  // pair -> expert bitmask: (0,1)(0,2)(0,3)(1,2)(1,3)(2,3)
  const int lut[6] = {3, 5, 9, 6, 10, 12};
  pm_s[pos] = lut[pid];
}

// gather token rows into sorted order while converting fp32 -> bf16
__global__ __launch_bounds__(256) void cvt_gather(const float4* __restrict__ hs,
                                                  const int* __restrict__ perm,
                                                  bf16x4* __restrict__ xb) {
  int pos = blockIdx.x;
  int tok = perm[pos];
  const float4* src = hs + (size_t)tok * 512;
  bf16x4* dst = xb + (size_t)pos * 512;
#pragma unroll
  for (int i = 0; i < 2; ++i) {
    int j = i * 256 + threadIdx.x;
    float4 v = src[j];
    bf16x4 o;
    o.x = (__bf16)v.x; o.y = (__bf16)v.y; o.z = (__bf16)v.z; o.w = (__bf16)v.w;
    dst[j] = o;
  }
}

// per-128-row-tile active-expert mask (OR of token pair-masks)
__global__ void tile_mask_kernel(const int* __restrict__ pm_s, int* __restrict__ tmask) {
  int t = threadIdx.x;  // 128 tiles, 1 block of 128 threads
  int m = 0;
  for (int i = 0; i < 128; ++i) m |= pm_s[t * 128 + i];
  tmask[t] = m;
}

// ---------------------------------------------------------------------------
// gemm_bt<MODE>: C = A[M,K] @ Bt[Nout,K]^T, 128x128 tile, BK=32,
// mfma_f32_16x16x32_bf16, global_load_lds width-16 staging (m97 structure).
// MODE 0: GEMM1 K=2048, Nout=8192 (A = sorted tokens): block exits if its
//         expert (bx>>4) inactive in row-tile; epilogue +b1, gelu, *combine.
// MODE 1: GEMM2 K=8192, Nout=2048: K-loop visits only active experts' ranges;
//         epilogue + sum_e comb*b2, scatter rows via perm.
// ---------------------------------------------------------------------------
template <int MODE>
__global__ __launch_bounds__(256) void gemm_bt(const __bf16* __restrict__ A,
                                               const __bf16* __restrict__ Bt,
                                               const float* __restrict__ bias,
                                               const float* __restrict__ cc,
                                               const int* __restrict__ tmask,
                                               const int* __restrict__ permc,
                                               void* __restrict__ outp) {
  constexpr int K = (MODE == 0) ? 2048 : 8192;
  __shared__ __bf16 ldsA[128 * 32];
  __shared__ __bf16 ldsB[128 * 32];

  const int tid = threadIdx.x;
  const int lane = tid & 63;
  const int wv = tid >> 6;
  const int bx = blockIdx.x, by = blockIdx.y;

  const int tm = tmask[by];
  if (MODE == 0) {
    if (!(tm & (1 << (bx >> 4)))) return;  // expert inactive for this row-tile
  }

  const int lrow = lane & 15;   // A-row / B-col within 16x16 tile
  const int quad = lane >> 4;   // k-group: k = quad*8 + j
  const int mbase = (wv >> 1) * 64;
  const int nbase = (wv & 1) * 64;

  f32x4 acc[4][4] = {};

  auto k_step = [&](int kb) {
    __syncthreads();  // protect LDS from previous iteration's readers
#pragma unroll
    for (int t = 0; t < 2; ++t) {
      int g = t * 256 + wv * 64 + lane;  // 16B-chunk id, 0..511
      int row = g >> 2, kc = g & 3;
      const __bf16* ga = A + (size_t)(by * 128 + row) * K + kb * 32 + kc * 8;
      const __bf16* gb = Bt + (size_t)(bx * 128 + row) * K + kb * 32 + kc * 8;
      int loff = t * 2048 + wv * 512;  // wave-uniform LDS base; HW adds lane*16B
      __builtin_amdgcn_global_load_lds((GV*)ga, (LV*)&ldsA[loff], 16, 0, 0);
      __builtin_amdgcn_global_load_lds((GV*)gb, (LV*)&ldsB[loff], 16, 0, 0);
    }
    __syncthreads();

    bf16x8 af[4], bfr[4];
#pragma unroll
    for (int i = 0; i < 4; ++i)
      af[i] = *(const bf16x8*)&ldsA[(mbase + i * 16 + lrow) * 32 + quad * 8];
#pragma unroll
    for (int i = 0; i < 4; ++i)
      bfr[i] = *(const bf16x8*)&ldsB[(nbase + i * 16 + lrow) * 32 + quad * 8];
#pragma unroll
    for (int mi = 0; mi < 4; ++mi)
#pragma unroll
      for (int ni = 0; ni < 4; ++ni)
        acc[mi][ni] = __builtin_amdgcn_mfma_f32_16x16x32_bf16(af[mi], bfr[ni],
                                                              acc[mi][ni], 0, 0, 0);
  };

  if (MODE == 0) {
    for (int kb = 0; kb < K / 32; ++kb) k_step(kb);
  } else {
    for (int e = 0; e < 4; ++e) {
      if (!(tm & (1 << e))) continue;  // wave-uniform: skip inactive expert's K range
      for (int kb = e * 64; kb < e * 64 + 64; ++kb) k_step(kb);
    }
  }

  // epilogue: C/D layout col = lane&15, row = quad*4 + reg  [m89/m91 verified]
  if (MODE == 0) {
    __bf16* out = (__bf16*)outp;
#pragma unroll
    for (int mi = 0; mi < 4; ++mi) {
#pragma unroll
      for (int ni = 0; ni < 4; ++ni) {
        int gcol = bx * 128 + nbase + ni * 16 + lrow;
        int e = gcol >> 11;
        int h = gcol & 2047;
        float b = bias[e * 2048 + h];
        f32x4 v = acc[mi][ni];
#pragma unroll
        for (int r = 0; r < 4; ++r) {
          int row = by * 128 + mbase + mi * 16 + quad * 4 + r;
          float xv = v[r] + b;
          float gl = 0.5f * xv * (1.0f + erff(xv * 0.70710678118654752440f));
          out[(size_t)row * 8192 + gcol] = (__bf16)(gl * cc[row * 4 + e]);
        }
      }
    }
  } else {
    float* out = (float*)outp;
    float bb[4][4];
#pragma unroll
    for (int ni = 0; ni < 4; ++ni) {
      int gcol = bx * 128 + nbase + ni * 16 + lrow;
#pragma unroll
      for (int e = 0; e < 4; ++e) bb[ni][e] = bias[e * 2048 + gcol];
    }
#pragma unroll
    for (int mi = 0; mi < 4; ++mi) {
#pragma unroll
      for (int r = 0; r < 4; ++r) {
        int row = by * 128 + mbase + mi * 16 + quad * 4 + r;
        int tok = permc[row];
        const float* cw = cc + (size_t)row * 4;
        float c0 = cw[0], c1 = cw[1], c2 = cw[2], c3 = cw[3];
#pragma unroll
        for (int ni = 0; ni < 4; ++ni) {
          int gcol = bx * 128 + nbase + ni * 16 + lrow;
          float s = acc[mi][ni][r] + c0 * bb[ni][0] + c1 * bb[ni][1] +
                    c2 * bb[ni][2] + c3 * bb[ni][3];
          out[(size_t)tok * 2048 + gcol] = s;
        }
      }
    }
  }
}

// ---------------------------------------------------------------------------
// launch
// ---------------------------------------------------------------------------
extern "C" void kernel_launch(void* const* d_in, const int* in_sizes, int n_in,
                              void* d_out, int out_size, void* d_ws, size_t ws_size,
                              hipStream_t stream) {
  const float* hs = (const float*)d_in[0];      // [8,2048,2048]
  const float* gate_w = (const float*)d_in[1];  // [4,2048]
  const float* w1 = (const float*)d_in[2];      // [4,2048,2048]
  const float* b1 = (const float*)d_in[3];      // [4,2048]
  const float* w2 = (const float*)d_in[4];      // [4,2048,2048]
  const float* b2 = (const float*)d_in[5];      // [4,2048]
  float* out = (float*)d_out;

  const int N = 16384, D = 2048, H = 2048, E = 4;
  const int CHUNK = 4096;

  char* p = (char*)d_ws;
  __bf16* xb_s = (__bf16*)p;  p += (size_t)N * D * 2;      //  64 MiB (sorted tokens)
  __bf16* w1t = (__bf16*)p;   p += (size_t)E * D * H * 2;  //  32 MiB  [e][h][d]
  __bf16* w2t = (__bf16*)p;   p += (size_t)E * H * H * 2;  //  32 MiB  [o][e*2048+h]
  float* comb = (float*)p;    p += (size_t)N * 4 * 4;      // 256 KiB (token order)
  float* comb_s = (float*)p;  p += (size_t)N * 4 * 4;      // 256 KiB (sorted)
  int* perm = (int*)p;        p += (size_t)N * 4;          //  64 KiB
  int* pairid = (int*)p;      p += (size_t)N * 4;          //  64 KiB
  int* pm_s = (int*)p;        p += (size_t)N * 4;          //  64 KiB
  int* meta = (int*)p;        p += 32 * 4;                 // cnt[8], cur[8], off[8]
  int* tmask = (int*)p;       p += 128 * 4;                // N/128 tiles
  __bf16* h1s = (__bf16*)p;                                //  64 MiB [CHUNK][E*H]

  hipMemsetAsync(meta, 0, 64, stream);  // zero cnt[8] + cur[8]
  transpose_cvt<2048, true><<<dim3(64, 64, 4), 256, 0, stream>>>(w1, w1t);
  transpose_cvt<8192, false><<<dim3(64, 64, 4), 256, 0, stream>>>(w2, w2t);
  router_kernel<<<dim3(N / 4), 256, 0, stream>>>(hs, gate_w, comb, pairid, meta);
  scan6<<<1, 1, 0, stream>>>(meta, meta + 16);
  assign_kernel<<<dim3(N / 256), 256, 0, stream>>>(pairid, (const float4*)comb,
                                                   meta + 16, meta + 8, perm,
                                                   (float4*)comb_s, pm_s);
  cvt_gather<<<dim3(N), 256, 0, stream>>>((const float4*)hs, perm, (bf16x4*)xb_s);
  tile_mask_kernel<<<1, 128, 0, stream>>>(pm_s, tmask);

  for (int c = 0; c < N / CHUNK; ++c) {
    const __bf16* Ax = xb_s + (size_t)c * CHUNK * D;
    const float* cc = comb_s + (size_t)c * CHUNK * 4;
    const int* tmc = tmask + c * (CHUNK / 128);
    gemm_bt<0><<<dim3(E * H / 128, CHUNK / 128), 256, 0, stream>>>(Ax, w1t, b1, cc,
                                                                   tmc, nullptr, h1s);
    gemm_bt<1><<<dim3(H / 128, CHUNK / 128), 256, 0, stream>>>(h1s, w2t, b2, cc, tmc,
                                                               perm + c * CHUNK, out);
  }
}